// Round 9
// baseline (432.357 us; speedup 1.0000x reference)
//
#include <hip/hip_runtime.h>
#include <stdint.h>

// Problem constants
#define M_BATCH 32768
#define N_OUT   1024
#define K_IN    1024

// GEMM tile (round-2 proven geometry)
#define BM 128
#define BN 128
#define BK 64
#define NT (K_IN / BK)   // 16

typedef __attribute__((ext_vector_type(8))) short  short8;
typedef __attribute__((ext_vector_type(4))) float  f32x4;

__device__ __forceinline__ unsigned short f2bf(float f) {
    __bf16 h = (__bf16)f;
    return __builtin_bit_cast(unsigned short, h);
}

typedef const __attribute__((address_space(1))) unsigned int* gas_ptr;
typedef __attribute__((address_space(3))) unsigned int*       las_ptr;

__device__ __forceinline__ void gload_lds16(const void* g, void* l) {
    // async global->LDS, 16B/lane; LDS dest = wave-uniform base + lane*16
    __builtin_amdgcn_global_load_lds((gas_ptr)g, (las_ptr)l, 16, 0, 0);
}

// ---------------------------------------------------------------------------
// Kernel 1: materialize W (bf16) from eigens.
// W[y*8+j][xb*8+c] = eigens[y][xb][(j-c)&7]
// ---------------------------------------------------------------------------
__global__ __launch_bounds__(256) void build_w(const float* __restrict__ eig,
                                               unsigned short* __restrict__ W) {
    int tid = blockIdx.x * 256 + threadIdx.x;   // 0..16383
    int y  = tid >> 7;
    int xb = tid & 127;
    const float* e = eig + (size_t)((y << 7) + xb) * 8;
    f32x4 e0 = *reinterpret_cast<const f32x4*>(e);
    f32x4 e1 = *reinterpret_cast<const f32x4*>(e + 4);
    float ev[8] = {e0[0], e0[1], e0[2], e0[3], e1[0], e1[1], e1[2], e1[3]};
#pragma unroll
    for (int j = 0; j < 8; ++j) {
        alignas(16) unsigned short wv[8];
#pragma unroll
        for (int c = 0; c < 8; ++c) wv[c] = f2bf(ev[(j - c) & 7]);
        *reinterpret_cast<uint4*>(W + (size_t)(y * 8 + j) * K_IN + xb * 8) =
            *reinterpret_cast<const uint4*>(wv);
    }
}

// ---------------------------------------------------------------------------
// Kernel 2: direct GEMM. C[M,N] = cvt_bf16(A_f32)[M,K] * W[N,K]^T, fp32 out.
// Round-2 stall structure EXACTLY (2x __syncthreads, no inline asm):
//   - B staged via global_load_lds, pre-swizzled source (round-2 verbatim,
//     measured 0 bank conflicts)
//   - A: NO LDS. Each lane loads its own MFMA A-fragments straight from
//     global f32 (same k-mapping the LDS read would produce: lane holds
//     row (lane&15), k-chunk (lane>>4)*8 .. +8), cvt f32->bf16 in the
//     COMPUTE phase where VALU overlaps MFMA (separate pipes).
//   - A-row reuse across the 8 N-blocks of an M-panel is served by L2
//     (XCD-aware swizzle keeps them on one XCD).
// ---------------------------------------------------------------------------
__global__ __launch_bounds__(256, 2) void gemm_direct(const float* __restrict__ A,
                                                      const unsigned short* __restrict__ W,
                                                      float* __restrict__ C) {
    __shared__ unsigned short Blds[BN * BK];    // 16 KiB only

    // XCD-aware bijective swizzle (nwg=2048, %8==0): the 8 N-blocks of one
    // M-panel run consecutively on one XCD -> A panel (512KB f32) L2-hits.
    const int bid  = blockIdx.x;
    const int swz  = (bid & 7) * 256 + (bid >> 3);
    const int nblk = swz & 7;
    const int mblk = swz >> 3;
    const int brow = mblk * BM;
    const int bcol = nblk * BN;

    const int tid  = threadIdx.x;
    const int lane = tid & 63;
    const int wv   = tid >> 6;                   // wave 0..3
    const int wm   = wv >> 1;
    const int wn   = wv & 1;

    f32x4 acc[4][4];
    const f32x4 zero = {0.f, 0.f, 0.f, 0.f};
#pragma unroll
    for (int i = 0; i < 4; ++i)
#pragma unroll
        for (int j = 0; j < 4; ++j) acc[i][j] = zero;

    // ---- B staging map (round-2 verbatim): wave wv stages 4 segments of 8
    // rows; lane l -> row l>>3, chunk (l&7)^(l>>3) (pre-swizzled source).
    const int lrow = lane >> 3;
    const int lchk = (lane & 7) ^ lrow;
    const unsigned short* Bbase = W + (size_t)(bcol + wv * 32 + lrow) * K_IN + lchk * 8;
    unsigned short* BldsBase = Blds + wv * 2048;

    // ---- A fragment base: lane owns row (wm*64 + lane&15), k-chunk
    // (lane>>4)*8. Fragment (mt, ks): 8 f32 at + mt*16*K + kt + ks*32.
    const float* Abase = A + (size_t)(brow + wm * 64 + (lane & 15)) * K_IN
                           + (lane >> 4) * 8;

    for (int t = 0; t < NT; ++t) {
        const int kt = t * BK;

        __syncthreads();                         // entry: prev tile consumed

        // ---- issue B(t) global_load_lds (4 per wave)
#pragma unroll
        for (int s = 0; s < 4; ++s)
            gload_lds16(Bbase + (size_t)(s * 8) * K_IN + kt, BldsBase + s * 512);

        // ---- issue A(t) fragment loads (16 x f32x4, register dest)
        f32x4 aR[4][2][2];
#pragma unroll
        for (int mt = 0; mt < 4; ++mt)
#pragma unroll
            for (int ks = 0; ks < 2; ++ks) {
                const float* s = Abase + (size_t)(mt * 16) * K_IN + kt + ks * 32;
                aR[mt][ks][0] = *reinterpret_cast<const f32x4*>(s);
                aR[mt][ks][1] = *reinterpret_cast<const f32x4*>(s + 4);
            }

        __syncthreads();                         // vmcnt(0): A landed, B in LDS

        // ---- compute: cvt overlaps MFMA; B-frag reads round-2 verbatim
#pragma unroll
        for (int ks = 0; ks < 2; ++ks) {
            short8 af[4];
#pragma unroll
            for (int mt = 0; mt < 4; ++mt) {
#pragma unroll
                for (int i = 0; i < 4; ++i) af[mt][i]     = (short)f2bf(aR[mt][ks][0][i]);
#pragma unroll
                for (int i = 0; i < 4; ++i) af[mt][i + 4] = (short)f2bf(aR[mt][ks][1][i]);
            }
            short8 bfr[4];
            const int cb = ks * 4 + (lane >> 4); // global 16B k-chunk 0..7
            const int sl = cb ^ (lane & 7);      // swizzled LDS slot
#pragma unroll
            for (int nt = 0; nt < 4; ++nt) {
                int row = wn * 64 + nt * 16 + (lane & 15);
                bfr[nt] = *reinterpret_cast<const short8*>(Blds + row * BK + sl * 8);
            }
#pragma unroll
            for (int mt = 0; mt < 4; ++mt)
#pragma unroll
                for (int nt = 0; nt < 4; ++nt)
                    acc[mt][nt] = __builtin_amdgcn_mfma_f32_16x16x32_bf16(
                        af[mt], bfr[nt], acc[mt][nt], 0, 0, 0);
        }
    }

    // ---- epilogue: C/D layout col = lane&15, row = (lane>>4)*4 + reg
#pragma unroll
    for (int mt = 0; mt < 4; ++mt) {
#pragma unroll
        for (int nt = 0; nt < 4; ++nt) {
            int col = bcol + wn * 64 + nt * 16 + (lane & 15);
#pragma unroll
            for (int r = 0; r < 4; ++r) {
                int row = brow + wm * 64 + mt * 16 + (lane >> 4) * 4 + r;
                C[(size_t)row * N_OUT + col] = acc[mt][nt][r];
            }
        }
    }
}

extern "C" void kernel_launch(void* const* d_in, const int* in_sizes, int n_in,
                              void* d_out, int out_size, void* d_ws, size_t ws_size,
                              hipStream_t stream) {
    const float* x   = (const float*)d_in[0];    // [32768,1024] f32
    const float* eig = (const float*)d_in[1];    // [128,128,8]  f32
    float* out = (float*)d_out;                  // [32768,1024] f32

    const size_t W_ELTS = (size_t)N_OUT * K_IN;  // 2 MiB bf16 scratch
    if (ws_size < W_ELTS * sizeof(unsigned short)) return;
    unsigned short* W = (unsigned short*)d_ws;

    hipLaunchKernelGGL(build_w, dim3(64), dim3(256), 0, stream, eig, W);
    hipLaunchKernelGGL(gemm_direct, dim3((M_BATCH / BM) * (N_OUT / BN)), dim3(256),
                       0, stream, x, W, out);
}